// Round 3
// baseline (346.502 us; speedup 1.0000x reference)
//
#include <hip/hip_runtime.h>

#define Bq   8
#define Cc   512
#define Ll   4096   // H*W
#define KV2  1024   // 2C
#define KS   4      // split-K factor for k1
#define KSL  (Ll / KS)

typedef _Float16 f16;
typedef __attribute__((ext_vector_type(4))) _Float16 f16x4;
typedef __attribute__((ext_vector_type(8))) _Float16 f16x8;
typedef __attribute__((ext_vector_type(4))) float    f32x4;

typedef const __attribute__((address_space(1))) void* gas_t;
typedef __attribute__((address_space(3))) void*       las_t;

__device__ __forceinline__ void gl16(const f16* g, f16* l) {
    __builtin_amdgcn_global_load_lds((gas_t)g, (las_t)l, 16, 0, 0);
}

// ===========================================================================
// P: fp32 -> f16 (hi only), vectorized
// ===========================================================================
__global__ __launch_bounds__(256) void p_cvt(const float* __restrict__ in,
                                             f16* __restrict__ hi, int n4) {
    int i = blockIdx.x * 256 + threadIdx.x;
    if (i >= n4) return;
    float4 v = ((const float4*)in)[i];
    f16x4 hv; hv[0] = (f16)v.x; hv[1] = (f16)v.y; hv[2] = (f16)v.z; hv[3] = (f16)v.w;
    ((f16x4*)hi)[i] = hv;
}

// --- W fp32 -> hi/lo fp16 (small) -----------------------------------------
__global__ __launch_bounds__(256) void p_split(const float* __restrict__ in,
                                               f16* __restrict__ hi,
                                               f16* __restrict__ lo, int n4) {
    int i = blockIdx.x * 256 + threadIdx.x;
    if (i >= n4) return;
    float4 v = ((const float4*)in)[i];
    f16 h0 = (f16)v.x, h1 = (f16)v.y, h2 = (f16)v.z, h3 = (f16)v.w;
    f16x4 hv; hv[0] = h0; hv[1] = h1; hv[2] = h2; hv[3] = h3;
    f16x4 lv;
    lv[0] = (f16)(v.x - (float)h0); lv[1] = (f16)(v.y - (float)h1);
    lv[2] = (f16)(v.z - (float)h2); lv[3] = (f16)(v.w - (float)h3);
    ((f16x4*)hi)[i] = hv;
    ((f16x4*)lo)[i] = lv;
}

// ===========================================================================
// P: KV = concat(sp,ms) -> KVhi [b][2C][L] f16 + KVT [b][L][2C] f16.
// Transpose via f16 LDS: scalar b16 transposed writes (4-way, cheap) +
// vector b128 row reads (stride 72 f16 = 36 words -> conflict-free pattern).
// ===========================================================================
__global__ __launch_bounds__(256) void p_kv(const float* __restrict__ sp,
                                            const float* __restrict__ ms,
                                            f16* __restrict__ kvhi,
                                            f16* __restrict__ kvt) {
    __shared__ __align__(16) f16 tile[64][72];   // [l][c], 144B row stride
    const int b = blockIdx.z, c0 = blockIdx.y * 64, l0 = blockIdx.x * 64;
    const int t = threadIdx.x;
    const int r = t >> 2, q = t & 3;             // c-row r, l-quarter q
    const float* src = (c0 + r < Cc)
        ? sp + ((size_t)b * Cc + c0 + r) * Ll
        : ms + ((size_t)b * Cc + (c0 + r - Cc)) * Ll;
    f16 h[16];
    #pragma unroll
    for (int i = 0; i < 4; ++i) {
        float4 v = *(const float4*)(src + l0 + q * 16 + i * 4);
        h[i * 4 + 0] = (f16)v.x; h[i * 4 + 1] = (f16)v.y;
        h[i * 4 + 2] = (f16)v.z; h[i * 4 + 3] = (f16)v.w;
    }
    {   // KVhi row-major: two 16B stores
        f16* dst = &kvhi[((size_t)b * KV2 + c0 + r) * Ll + l0 + q * 16];
        *(f16x8*)dst       = *(const f16x8*)&h[0];
        *(f16x8*)(dst + 8) = *(const f16x8*)&h[8];
    }
    #pragma unroll
    for (int e = 0; e < 16; ++e)                 // transposed scalar writes
        tile[q * 16 + e][r] = h[e];
    __syncthreads();
    const int lr_ = t >> 3, g = t & 7;
    #pragma unroll
    for (int p = 0; p < 2; ++p) {
        const int l = lr_ + 32 * p;
        f16x8 o = *(const f16x8*)&tile[l][g * 8];
        *(f16x8*)&kvt[((size_t)b * Ll + l0 + l) * KV2 + c0 + g * 8] = o;
    }
}

// ===========================================================================
// 256x256-tile NT MFMA GEMM, 8-phase schedule (T1+T2+T3+T4+T5):
//   - 512 threads = 8 waves (2M x 4N), per-wave C = 128x64, BK=64
//   - LDS: ring of 8 half-tile slots (128 rows x 64 f16 = 16KB) = 128KB
//     half h = 4*T + type, type: 0=B0,1=B1,2=A0,3=A1; slot = h&7
//   - stage order (steady): A1(T+1)@p0, B0(T+2)@p1, B1(T+2)@p2, A0(T+2)@p3
//   - counted vmcnt(6) only at tile boundary (3 half-tiles in flight),
//     vmcnt(0) only for the last two boundaries
//   - 3-bit XOR LDS swizzle (verified conflict-free in round 1)
// EPI 0: f16 out * (scale*L^-0.5)  (k1, split-K slice KSV)
// EPI 2: fp32 out + bias[m]        (k4)
// ===========================================================================
template<int KD, int NBN, int EPI, int KSV>
__global__ __launch_bounds__(512, 2) void gemm256(
    const f16* __restrict__ Ah, size_t sAb, int lda,
    const f16* __restrict__ Bh, size_t sBb, int ldb,
    const float* __restrict__ scale_ptr, const float* __restrict__ bias,
    float* __restrict__ Cf, f16* __restrict__ Chi,
    size_t sCb, size_t sliceC, int ldc)
{
    constexpr int NT = KD / 64;
    __shared__ __align__(16) f16 ring[8][128 * 64];

    // XCD-aware bijective swizzle (grid = 256 = 32/XCD)
    int wg = blockIdx.x;
    const int chunk = (int)gridDim.x >> 3;
    wg = (wg & 7) * chunk + (wg >> 3);
    const int m0 = (wg & 1) * 256; wg >>= 1;
    const int n0 = (wg % NBN) * 256; wg /= NBN;
    const int b = wg / KSV, s = wg % KSV;

    const int t = threadIdx.x;
    const int w = t >> 6, lane = t & 63;
    const int quad = lane >> 4, lr = lane & 15;
    const int wm = (w >> 2) * 128, wn = (w & 3) * 64;
    const int tA = 2 + (w >> 2);           // wave's A half-type
    const int tB = (w & 3) >> 1;           // wave's B half-type
    const int brow = (w & 1) * 64;         // B row base within half
    const int srow = lane >> 3, sslot = (lane & 7) ^ srow;
    const int x7 = lr & 7;

    const f16* gA = Ah + (size_t)b * sAb + (size_t)s * KD
                  + (size_t)(m0 + w * 8 + srow) * lda + sslot * 8;
    const f16* gB = Bh + (size_t)b * sBb + (size_t)s * KD
                  + (size_t)(n0 + w * 8 + srow) * ldb + sslot * 8;
    f16* const ld0 = &ring[0][0] + (w * 8) * 64;   // wave-uniform LDS base

    auto stA = [&](int tile, int half) {
        if (tile >= NT) return;
        f16* d = ld0 + ((tile * 4 + 2 + half) & 7) * (128 * 64);
        const f16* g = gA + (size_t)(half * 128) * lda + tile * 64;
        gl16(g, d);
        gl16(g + (size_t)64 * lda, d + 64 * 64);
    };
    auto stB = [&](int tile, int half) {
        if (tile >= NT) return;
        f16* d = ld0 + ((tile * 4 + half) & 7) * (128 * 64);
        const f16* g = gB + (size_t)(half * 128) * ldb + tile * 64;
        gl16(g, d);
        gl16(g + (size_t)64 * ldb, d + 64 * 64);
    };

    f32x4 acc[8][4];
    #pragma unroll
    for (int i = 0; i < 8; ++i)
        #pragma unroll
        for (int j = 0; j < 4; ++j) {
            acc[i][j][0] = 0.f; acc[i][j][1] = 0.f;
            acc[i][j][2] = 0.f; acc[i][j][3] = 0.f;
        }

    // ---- prologue: issue tile0 fully + B0,B1,A0 of tile1; confirm tile0
    stB(0, 0); stB(0, 1); stA(0, 0); stA(0, 1);
    stB(1, 0); stB(1, 1); stA(1, 0);
    asm volatile("s_waitcnt vmcnt(6)" ::: "memory");
    __builtin_amdgcn_s_barrier();

    f16x8 a[4][2], bf[4][2];

    #pragma unroll 2
    for (int T = 0; T < NT; ++T) {
        const f16* sAp = &ring[(T * 4 + tA) & 7][0];
        const f16* sBp = &ring[(T * 4 + tB) & 7][0];

        // ---------- phase 0: read A(i0-3) + all B frags; stage A1(T+1)
        #pragma unroll
        for (int ii = 0; ii < 4; ++ii)
            #pragma unroll
            for (int ks = 0; ks < 2; ++ks)
                a[ii][ks] = *(const f16x8*)&sAp[(ii * 16 + lr) * 64
                             + ((((ks << 2) | quad) ^ x7) << 3)];
        #pragma unroll
        for (int j = 0; j < 4; ++j)
            #pragma unroll
            for (int ks = 0; ks < 2; ++ks)
                bf[j][ks] = *(const f16x8*)&sBp[(brow + j * 16 + lr) * 64
                             + ((((ks << 2) | quad) ^ x7) << 3)];
        stA(T + 1, 1);
        asm volatile("s_waitcnt lgkmcnt(0)" ::: "memory");
        __builtin_amdgcn_s_barrier();
        __builtin_amdgcn_s_setprio(1);
        #pragma unroll
        for (int ii = 0; ii < 4; ++ii)
            #pragma unroll
            for (int j = 0; j < 2; ++j)
                #pragma unroll
                for (int ks = 0; ks < 2; ++ks)
                    acc[ii][j] = __builtin_amdgcn_mfma_f32_16x16x32_f16(
                                     a[ii][ks], bf[j][ks], acc[ii][j], 0, 0, 0);
        __builtin_amdgcn_s_setprio(0);
        __builtin_amdgcn_s_barrier();

        // ---------- phase 1: stage B0(T+2); MFMA q1 (i0-3 x j2-3)
        stB(T + 2, 0);
        __builtin_amdgcn_s_barrier();
        __builtin_amdgcn_s_setprio(1);
        #pragma unroll
        for (int ii = 0; ii < 4; ++ii)
            #pragma unroll
            for (int j = 0; j < 2; ++j)
                #pragma unroll
                for (int ks = 0; ks < 2; ++ks)
                    acc[ii][2 + j] = __builtin_amdgcn_mfma_f32_16x16x32_f16(
                                     a[ii][ks], bf[2 + j][ks], acc[ii][2 + j], 0, 0, 0);
        __builtin_amdgcn_s_setprio(0);
        __builtin_amdgcn_s_barrier();

        // ---------- phase 2: read A(i4-7); stage B1(T+2); MFMA q2
        #pragma unroll
        for (int ii = 0; ii < 4; ++ii)
            #pragma unroll
            for (int ks = 0; ks < 2; ++ks)
                a[ii][ks] = *(const f16x8*)&sAp[((ii + 4) * 16 + lr) * 64
                             + ((((ks << 2) | quad) ^ x7) << 3)];
        stB(T + 2, 1);
        asm volatile("s_waitcnt lgkmcnt(0)" ::: "memory");
        __builtin_amdgcn_s_barrier();
        __builtin_amdgcn_s_setprio(1);
        #pragma unroll
        for (int ii = 0; ii < 4; ++ii)
            #pragma unroll
            for (int j = 0; j < 2; ++j)
                #pragma unroll
                for (int ks = 0; ks < 2; ++ks)
                    acc[4 + ii][j] = __builtin_amdgcn_mfma_f32_16x16x32_f16(
                                     a[ii][ks], bf[j][ks], acc[4 + ii][j], 0, 0, 0);
        __builtin_amdgcn_s_setprio(0);
        __builtin_amdgcn_s_barrier();

        // ---------- phase 3: stage A0(T+2); boundary vmcnt; MFMA q3
        stA(T + 2, 0);
        if (T + 2 < NT) { asm volatile("s_waitcnt vmcnt(6)" ::: "memory"); }
        else            { asm volatile("s_waitcnt vmcnt(0)" ::: "memory"); }
        __builtin_amdgcn_s_barrier();
        __builtin_amdgcn_s_setprio(1);
        #pragma unroll
        for (int ii = 0; ii < 4; ++ii)
            #pragma unroll
            for (int j = 0; j < 2; ++j)
                #pragma unroll
                for (int ks = 0; ks < 2; ++ks)
                    acc[4 + ii][2 + j] = __builtin_amdgcn_mfma_f32_16x16x32_f16(
                                     a[ii][ks], bf[2 + j][ks], acc[4 + ii][2 + j], 0, 0, 0);
        __builtin_amdgcn_s_setprio(0);
        __builtin_amdgcn_s_barrier();
    }

    if constexpr (EPI == 0) {
        const float alpha = scale_ptr[0] * 0.015625f;
        f16* Cs = Chi + (size_t)s * sliceC + (size_t)b * sCb;
        #pragma unroll
        for (int i = 0; i < 8; ++i)
            #pragma unroll
            for (int j = 0; j < 4; ++j) {
                const int n = n0 + wn + j * 16 + lr;
                #pragma unroll
                for (int r = 0; r < 4; ++r) {
                    const int m = m0 + wm + i * 16 + quad * 4 + r;
                    Cs[(size_t)m * ldc + n] = (f16)(alpha * acc[i][j][r]);
                }
            }
    } else {
        float* Co = Cf + (size_t)b * sCb;
        #pragma unroll
        for (int i = 0; i < 8; ++i)
            #pragma unroll
            for (int j = 0; j < 4; ++j) {
                const int n = n0 + wn + j * 16 + lr;
                #pragma unroll
                for (int r = 0; r < 4; ++r) {
                    const int m = m0 + wm + i * 16 + quad * 4 + r;
                    Co[(size_t)m * ldc + n] = acc[i][j][r] + bias[m];
                }
            }
    }
}

// ===========================================================================
// 128x128-tile NT MFMA GEMM (round-1 structure) — kept for K3 (LO path).
// ===========================================================================
template<int KD, int NBN, int EPI, bool LO, int KSV>
__global__ __launch_bounds__(256, 3) void gemm_mfma(
    const f16* __restrict__ Ah, const f16* __restrict__ Al, size_t sAb, int lda,
    const f16* __restrict__ Bh, size_t sBb, int ldb,
    const float* __restrict__ scale_ptr, const float* __restrict__ bias,
    float* __restrict__ Cf, f16* __restrict__ Chi,
    size_t sCb, size_t sliceC, int ldc)
{
    __shared__ __align__(16) f16 sA[128 * 64];
    __shared__ __align__(16) f16 sB[128 * 64];
    __shared__ __align__(16) f16 sL[LO ? 128 * 64 : 8];

    int wg = blockIdx.x;
    const int chunk = (int)gridDim.x >> 3;
    wg = (wg & 7) * chunk + (wg >> 3);
    const int m0 = (wg & 3) * 128; wg >>= 2;
    const int n0 = (wg % NBN) * 128; wg /= NBN;
    const int b  = wg / KSV, s = wg % KSV;

    const int t = threadIdx.x;
    const int w = t >> 6, lane = t & 63;
    const int quad = lane >> 4, lr = lane & 15;
    const int wm = (w & 1) * 64, wn = (w >> 1) * 64;
    const int sr = lane >> 3, sc = lane & 7;
    const int swb = (sc ^ sr) << 3;
    const int x7 = lr & 7;

    const f16* gA = Ah + (size_t)b * sAb + (size_t)s * KD
                  + (size_t)(m0 + w * 8 + sr) * lda + swb;
    const f16* gB = Bh + (size_t)b * sBb + (size_t)s * KD
                  + (size_t)(n0 + w * 8 + sr) * ldb + swb;
    const f16* gL = LO ? (Al + (size_t)(m0 + w * 8 + sr) * lda + swb) : nullptr;

    f32x4 acc[4][4];
    #pragma unroll
    for (int i = 0; i < 4; ++i)
        #pragma unroll
        for (int j = 0; j < 4; ++j) {
            acc[i][j][0] = 0.f; acc[i][j][1] = 0.f;
            acc[i][j][2] = 0.f; acc[i][j][3] = 0.f;
        }

    for (int k0 = 0; k0 < KD; k0 += 64) {
        #pragma unroll
        for (int i = 0; i < 4; ++i) {
            gl16(gA + k0 + (size_t)(i * 32) * lda, &sA[(i * 32 + w * 8) * 64]);
            gl16(gB + k0 + (size_t)(i * 32) * ldb, &sB[(i * 32 + w * 8) * 64]);
            if constexpr (LO)
                gl16(gL + k0 + (size_t)(i * 32) * lda, &sL[(i * 32 + w * 8) * 64]);
        }
        asm volatile("s_waitcnt vmcnt(0)" ::: "memory");
        __syncthreads();
        #pragma unroll
        for (int ks = 0; ks < 2; ++ks) {
            f16x8 af[4], bfr[4];
            #pragma unroll
            for (int i = 0; i < 4; ++i)
                af[i] = *(const f16x8*)&sA[(wm + i * 16 + lr) * 64
                         + ((((ks << 2) | quad) ^ x7) << 3)];
            #pragma unroll
            for (int j = 0; j < 4; ++j)
                bfr[j] = *(const f16x8*)&sB[(wn + j * 16 + lr) * 64
                         + ((((ks << 2) | quad) ^ x7) << 3)];
            #pragma unroll
            for (int i = 0; i < 4; ++i)
                #pragma unroll
                for (int j = 0; j < 4; ++j)
                    acc[i][j] = __builtin_amdgcn_mfma_f32_16x16x32_f16(
                                    af[i], bfr[j], acc[i][j], 0, 0, 0);
            if constexpr (LO) {
                f16x8 lf[4];
                #pragma unroll
                for (int i = 0; i < 4; ++i)
                    lf[i] = *(const f16x8*)&sL[(wm + i * 16 + lr) * 64
                             + ((((ks << 2) | quad) ^ x7) << 3)];
                #pragma unroll
                for (int i = 0; i < 4; ++i)
                    #pragma unroll
                    for (int j = 0; j < 4; ++j)
                        acc[i][j] = __builtin_amdgcn_mfma_f32_16x16x32_f16(
                                        lf[i], bfr[j], acc[i][j], 0, 0, 0);
            }
        }
        __syncthreads();
    }

    if constexpr (EPI == 0) {
        const float alpha = scale_ptr[0] * 0.015625f;
        f16* Cs = Chi + (size_t)s * sliceC + (size_t)b * sCb;
        #pragma unroll
        for (int i = 0; i < 4; ++i)
            #pragma unroll
            for (int j = 0; j < 4; ++j) {
                const int n = n0 + wn + j * 16 + lr;
                #pragma unroll
                for (int r = 0; r < 4; ++r) {
                    const int m = m0 + wm + i * 16 + quad * 4 + r;
                    Cs[(size_t)m * ldc + n] = (f16)(alpha * acc[i][j][r]);
                }
            }
    } else if constexpr (EPI == 1) {
        f16* Cs = Chi + (size_t)b * sCb;
        #pragma unroll
        for (int i = 0; i < 4; ++i)
            #pragma unroll
            for (int j = 0; j < 4; ++j) {
                const int n = n0 + wn + j * 16 + lr;
                #pragma unroll
                for (int r = 0; r < 4; ++r) {
                    const int m = m0 + wm + i * 16 + quad * 4 + r;
                    Cs[(size_t)m * ldc + n] = (f16)acc[i][j][r];
                }
            }
    } else {
        float* Co = Cf + (size_t)b * sCb;
        #pragma unroll
        for (int i = 0; i < 4; ++i)
            #pragma unroll
            for (int j = 0; j < 4; ++j) {
                const int n = n0 + wn + j * 16 + lr;
                #pragma unroll
                for (int r = 0; r < 4; ++r) {
                    const int m = m0 + wm + i * 16 + quad * 4 + r;
                    Co[(size_t)m * ldc + n] = acc[i][j][r] + bias[m];
                }
            }
    }
}

// ===========================================================================
// K2: sum KS f16 partials, softmax over last dim (1024), write attnT f16
// ===========================================================================
__global__ __launch_bounds__(256) void k2_softmax_t(const f16* __restrict__ attnP,
                                                    f16* __restrict__ attnT) {
    __shared__ float rmax[16], rinv[16];
    __shared__ __align__(16) f16 tile[16][68];
    const int b = blockIdx.y, c0 = blockIdx.x * 16;
    const int t = threadIdx.x, w = t >> 6, lane = t & 63;
    const size_t sS = (size_t)Bq * Cc * KV2;

    for (int rr = 0; rr < 4; ++rr) {
        const int r = w * 4 + rr;
        const f16* base = attnP + ((size_t)b * Cc + c0 + r) * KV2;
        float v[16];
        #pragma unroll
        for (int i = 0; i < 2; ++i) {
            f16x8 u = *(const f16x8*)(base + (lane + 64 * i) * 8);
            #pragma unroll
            for (int j = 0; j < 8; ++j) v[i * 8 + j] = (float)u[j];
        }
        #pragma unroll
        for (int s = 1; s < KS; ++s) {
            const f16* bs = base + (size_t)s * sS;
            #pragma unroll
            for (int i = 0; i < 2; ++i) {
                f16x8 u = *(const f16x8*)(bs + (lane + 64 * i) * 8);
                #pragma unroll
                for (int j = 0; j < 8; ++j) v[i * 8 + j] += (float)u[j];
            }
        }
        float m = -3.4e38f;
        #pragma unroll
        for (int i = 0; i < 16; ++i) m = fmaxf(m, v[i]);
        #pragma unroll
        for (int off = 32; off; off >>= 1) m = fmaxf(m, __shfl_xor(m, off));
        float s = 0.f;
        #pragma unroll
        for (int i = 0; i < 16; ++i) s += __expf(v[i] - m);
        #pragma unroll
        for (int off = 32; off; off >>= 1) s += __shfl_xor(s, off);
        if (lane == 0) { rmax[r] = m; rinv[r] = 1.0f / s; }
    }
    __syncthreads();

    const int r2 = t >> 4, cn = (t & 15) * 4;
    const int n4 = t >> 2, q = t & 3;
    for (int nt = 0; nt < 16; ++nt) {
        const f16* base = attnP + ((size_t)b * Cc + c0 + r2) * KV2 + nt * 64 + cn;
        float vx[4];
        {
            f16x4 u = *(const f16x4*)base;
            #pragma unroll
            for (int j = 0; j < 4; ++j) vx[j] = (float)u[j];
        }
        #pragma unroll
        for (int s = 1; s < KS; ++s) {
            f16x4 u = *(const f16x4*)(base + (size_t)s * sS);
            #pragma unroll
            for (int j = 0; j < 4; ++j) vx[j] += (float)u[j];
        }
        const float m = rmax[r2], iv = rinv[r2];
        f16x4 hv;
        hv[0] = (f16)(__expf(vx[0] - m) * iv); hv[1] = (f16)(__expf(vx[1] - m) * iv);
        hv[2] = (f16)(__expf(vx[2] - m) * iv); hv[3] = (f16)(__expf(vx[3] - m) * iv);
        *(f16x4*)&tile[r2][cn] = hv;
        __syncthreads();
        f16x4 o;
        o[0] = tile[q * 4 + 0][n4]; o[1] = tile[q * 4 + 1][n4];
        o[2] = tile[q * 4 + 2][n4]; o[3] = tile[q * 4 + 3][n4];
        *(f16x4*)&attnT[((size_t)b * KV2 + nt * 64 + n4) * Cc + c0 + q * 4] = o;
        __syncthreads();
    }
}

// ===========================================================================
// FALLBACK PATH (fp32, needs only 33.6 MB)
// ===========================================================================
#define BM 64
#define BN 64
#define BK 32
#define PAD 4

__device__ __forceinline__ const float* kv_row(const float* __restrict__ sp,
                                               const float* __restrict__ ms,
                                               int b, int k) {
    return (k < Cc) ? (sp + ((size_t)b * Cc + k) * Ll)
                    : (ms + ((size_t)b * Cc + (k - Cc)) * Ll);
}

__global__ __launch_bounds__(256) void k1_logits(const float* __restrict__ x,
                                                 const float* __restrict__ sp,
                                                 const float* __restrict__ ms,
                                                 const float* __restrict__ scale,
                                                 float* __restrict__ attn) {
    __shared__ __align__(16) float As[BK][BM + PAD];
    __shared__ __align__(16) float Bs[BK][BN + PAD];
    const int b = blockIdx.z, m0 = blockIdx.y * BM, n0 = blockIdx.x * BN;
    const int t = threadIdx.x, tx = t & 15, ty = t >> 4, q = t & 7, r = t >> 3;
    const float alpha = scale[0] * (1.0f / 64.0f);
    const float* Abase = x + (size_t)b * Cc * Ll;
    float acc[4][4] = {};
    for (int k0 = 0; k0 < Ll; k0 += BK) {
        #pragma unroll
        for (int hh = 0; hh < 2; ++hh) {
            const int rw = r + 32 * hh;
            float4 v = *(const float4*)(Abase + (size_t)(m0 + rw) * Ll + k0 + 4 * q);
            As[4*q+0][rw] = v.x; As[4*q+1][rw] = v.y; As[4*q+2][rw] = v.z; As[4*q+3][rw] = v.w;
        }
        #pragma unroll
        for (int hh = 0; hh < 2; ++hh) {
            const int rw = r + 32 * hh;
            const float* Brow = kv_row(sp, ms, b, n0 + rw);
            float4 v = *(const float4*)(Brow + k0 + 4 * q);
            Bs[4*q+0][rw] = v.x; Bs[4*q+1][rw] = v.y; Bs[4*q+2][rw] = v.z; Bs[4*q+3][rw] = v.w;
        }
        __syncthreads();
        #pragma unroll
        for (int k = 0; k < BK; ++k) {
            float a[4], bb[4];
            *(float4*)a  = *(const float4*)&As[k][4 * ty];
            *(float4*)bb = *(const float4*)&Bs[k][4 * tx];
            #pragma unroll
            for (int i = 0; i < 4; ++i)
                #pragma unroll
                for (int j = 0; j < 4; ++j) acc[i][j] += a[i] * bb[j];
        }
        __syncthreads();
    }
    #pragma unroll
    for (int i = 0; i < 4; ++i) {
        const int m = m0 + 4 * ty + i;
        float4 o;
        o.x = alpha * acc[i][0]; o.y = alpha * acc[i][1];
        o.z = alpha * acc[i][2]; o.w = alpha * acc[i][3];
        *(float4*)(attn + ((size_t)b * Cc + m) * KV2 + n0 + 4 * tx) = o;
    }
}

__global__ __launch_bounds__(256) void k2_softmax(float* __restrict__ attn) {
    float* p = attn + (size_t)blockIdx.x * KV2;
    const int t = threadIdx.x, lane = t & 63, wv = t >> 6;
    float4 v = ((const float4*)p)[t];
    float m = fmaxf(fmaxf(v.x, v.y), fmaxf(v.z, v.w));
    #pragma unroll
    for (int off = 32; off; off >>= 1) m = fmaxf(m, __shfl_down(m, off));
    __shared__ float redm[4];
    if (lane == 0) redm[wv] = m;
    __syncthreads();
    m = fmaxf(fmaxf(redm[0], redm[1]), fmaxf(redm[2], redm[3]));
    v.x = __expf(v.x - m); v.y = __expf(v.y - m);
    v.z = __expf(v.z - m); v.w = __expf(v.w - m);
    float s = v.x + v.y + v.z + v.w;
    #pragma unroll
    for (int off = 32; off; off >>= 1) s += __shfl_down(s, off);
    __shared__ float reds[4];
    if (lane == 0) reds[wv] = s;
    __syncthreads();
    s = reds[0] + reds[1] + reds[2] + reds[3];
    const float inv = 1.0f / s;
    v.x *= inv; v.y *= inv; v.z *= inv; v.w *= inv;
    ((float4*)p)[t] = v;
}

__global__ __launch_bounds__(256) void k3_wattn(const float* __restrict__ W,
                                                const float* __restrict__ attn,
                                                float* __restrict__ attn2) {
    __shared__ __align__(16) float As[BK][BM + PAD];
    __shared__ __align__(16) float Bs[BK][BN];
    const int b = blockIdx.z, m0 = blockIdx.y * BM, n0 = blockIdx.x * BN;
    const int t = threadIdx.x, tx = t & 15, ty = t >> 4;
    const int q = t & 7, r = t >> 3, c4 = t & 15, kr = t >> 4;
    const float* Bbase = attn + (size_t)b * Cc * KV2;
    float acc[4][4] = {};
    for (int k0 = 0; k0 < Cc; k0 += BK) {
        #pragma unroll
        for (int hh = 0; hh < 2; ++hh) {
            const int rw = r + 32 * hh;
            float4 v = *(const float4*)(W + (size_t)(m0 + rw) * Cc + k0 + 4 * q);
            As[4*q+0][rw] = v.x; As[4*q+1][rw] = v.y; As[4*q+2][rw] = v.z; As[4*q+3][rw] = v.w;
        }
        #pragma unroll
        for (int hh = 0; hh < 2; ++hh) {
            const int k = kr + 16 * hh;
            float4 v = *(const float4*)(Bbase + (size_t)(k0 + k) * KV2 + n0 + 4 * c4);
            *(float4*)&Bs[k][4 * c4] = v;
        }
        __syncthreads();
        #pragma unroll
        for (int k = 0; k < BK; ++k) {
            float a[4], bb[4];
            *(float4*)a  = *(const float4*)&As[k][4 * ty];
            *(float4*)bb = *(const float4*)&Bs[k][4 * tx];
            #pragma unroll
            for (int i = 0; i < 4; ++i)
                #pragma unroll
                for (int j = 0; j < 4; ++j) acc[i][j] += a[i] * bb[j];
        }
        __syncthreads();
    }
    #pragma unroll
    for (int i = 0; i < 4; ++i) {
        const int m = m0 + 4 * ty + i;
        float4 o;
        o.x = acc[i][0]; o.y = acc[i][1]; o.z = acc[i][2]; o.w = acc[i][3];
        *(float4*)(attn2 + ((size_t)b * Cc + m) * KV2 + n0 + 4 * tx) = o;
    }
}

__global__ __launch_bounds__(256) void k4_out(const float* __restrict__ attn2,
                                              const float* __restrict__ sp,
                                              const float* __restrict__ ms,
                                              const float* __restrict__ bias,
                                              float* __restrict__ out) {
    __shared__ __align__(16) float As[BK][BM + PAD];
    __shared__ __align__(16) float Bs[BK][BN];
    const int b = blockIdx.z, m0 = blockIdx.y * BM, n0 = blockIdx.x * BN;
    const int t = threadIdx.x, tx = t & 15, ty = t >> 4;
    const int q = t & 7, r = t >> 3, c4 = t & 15, kr = t >> 4;
    const float* Abase = attn2 + (size_t)b * Cc * KV2;
    float acc[4][4] = {};
    for (int k0 = 0; k0 < KV2; k0 += BK) {
        #pragma unroll
        for (int hh = 0; hh < 2; ++hh) {
            const int rw = r + 32 * hh;
            float4 v = *(const float4*)(Abase + (size_t)(m0 + rw) * KV2 + k0 + 4 * q);
            As[4*q+0][rw] = v.x; As[4*q+1][rw] = v.y; As[4*q+2][rw] = v.z; As[4*q+3][rw] = v.w;
        }
        #pragma unroll
        for (int hh = 0; hh < 2; ++hh) {
            const int k = kr + 16 * hh;
            const float* Brow = kv_row(sp, ms, b, k0 + k);
            float4 v = *(const float4*)(Brow + n0 + 4 * c4);
            *(float4*)&Bs[k][4 * c4] = v;
        }
        __syncthreads();
        #pragma unroll
        for (int k = 0; k < BK; ++k) {
            float a[4], bb[4];
            *(float4*)a  = *(const float4*)&As[k][4 * ty];
            *(float4*)bb = *(const float4*)&Bs[k][4 * tx];
            #pragma unroll
            for (int i = 0; i < 4; ++i)
                #pragma unroll
                for (int j = 0; j < 4; ++j) acc[i][j] += a[i] * bb[j];
        }
        __syncthreads();
    }
    #pragma unroll
    for (int i = 0; i < 4; ++i) {
        const int m = m0 + 4 * ty + i;
        const float bm = bias[m];
        float4 o;
        o.x = acc[i][0] + bm; o.y = acc[i][1] + bm;
        o.z = acc[i][2] + bm; o.w = acc[i][3] + bm;
        *(float4*)(out + ((size_t)b * Cc + m) * Ll + n0 + 4 * tx) = o;
    }
}

// ===========================================================================
extern "C" void kernel_launch(void* const* d_in, const int* in_sizes, int n_in,
                              void* d_out, int out_size, void* d_ws, size_t ws_size,
                              hipStream_t stream) {
    const float* x     = (const float*)d_in[0];
    const float* sp    = (const float*)d_in[1];
    const float* ms    = (const float*)d_in[2];
    const float* scale = (const float*)d_in[3];
    const float* W     = (const float*)d_in[4];
    const float* bias  = (const float*)d_in[5];
    float* out = (float*)d_out;

    const size_t NEED = 219152384;
    if (ws_size >= NEED) {
        char* ws = (char*)d_ws;
        f16* attnP = (f16*)ws;                      // KS*B*C*2C f16 = 33,554,432
        f16* Xhi   = (f16*)(ws + 33554432);         // 33,554,432
        f16* KVhi  = (f16*)(ws + 67108864);         // 67,108,864
        f16* KVT   = (f16*)(ws + 134217728);        // 67,108,864
        f16* Whi   = (f16*)(ws + 201326592);        //    524,288
        f16* Wlo   = (f16*)(ws + 201850880);        //    524,288
        f16* attnT = (f16*)(ws + 202375168);        //  8,388,608
        f16* A2hi  = (f16*)(ws + 210763776);        //  8,388,608

        dim3 blk(256);
        p_cvt  <<<dim3(16384),                 blk, 0, stream>>>(x, Xhi, Bq * Cc * Ll / 4);
        p_kv   <<<dim3(Ll / 64, KV2 / 64, Bq), blk, 0, stream>>>(sp, ms, KVhi, KVT);
        p_split<<<dim3(256),                   blk, 0, stream>>>(W, Whi, Wlo, Cc * Cc / 4);

        // K1: attnP[s][b][m][n] = alpha * X[b,m,:] . KV[b,n,:]  (split-K=4)
        gemm256<KSL, KV2 / 256, 0, KS>
            <<<dim3(2 * (KV2 / 256) * Bq * KS), dim3(512), 0, stream>>>(
            Xhi, (size_t)Cc * Ll, Ll,
            KVhi, (size_t)KV2 * Ll, Ll,
            scale, nullptr, nullptr, attnP,
            (size_t)Cc * KV2, (size_t)Bq * Cc * KV2, KV2);

        k2_softmax_t<<<dim3(Cc / 16, Bq), blk, 0, stream>>>(attnP, attnT);

        // K3: A2[b][m][k] = (Whi+Wlo)[m,:] . attnT[b,k,:]
        gemm_mfma<Cc, KV2 / 128, 1, true, 1>
            <<<dim3(4 * (KV2 / 128) * Bq), blk, 0, stream>>>(
            Whi, Wlo, (size_t)0, Cc,
            attnT, (size_t)KV2 * Cc, Cc,
            nullptr, nullptr, nullptr, A2hi,
            (size_t)Cc * KV2, (size_t)0, KV2);

        // K4: out[b][m][l] = A2[b,m,:] . KVT[b,l,:] + bias[m]
        gemm256<KV2, Ll / 256, 2, 1>
            <<<dim3(2 * (Ll / 256) * Bq), dim3(512), 0, stream>>>(
            A2hi, (size_t)Cc * KV2, KV2,
            KVT, (size_t)Ll * KV2, KV2,
            nullptr, bias, out, nullptr,
            (size_t)Cc * Ll, (size_t)0, Ll);
    } else {
        float* attn  = (float*)d_ws;
        float* attn2 = attn + (size_t)Bq * Cc * KV2;
        dim3 blk(256);
        k1_logits <<<dim3(KV2 / BN, Cc / BM, Bq), blk, 0, stream>>>(x, sp, ms, scale, attn);
        k2_softmax<<<dim3(Bq * Cc),               blk, 0, stream>>>(attn);
        k3_wattn  <<<dim3(KV2 / BN, Cc / BM, Bq), blk, 0, stream>>>(W, attn, attn2);
        k4_out    <<<dim3(Ll / BN, Cc / BM, Bq), blk, 0, stream>>>(attn2, sp, ms, bias, out);
    }
}

// Round 4
// 338.765 us; speedup vs baseline: 1.0228x; 1.0228x over previous
//
#include <hip/hip_runtime.h>

#define Bq   8
#define Cc   512
#define Ll   4096   // H*W
#define KV2  1024   // 2C
#define KS   4      // split-K factor for k1
#define KSL  (Ll / KS)

typedef _Float16 f16;
typedef __attribute__((ext_vector_type(4))) _Float16 f16x4;
typedef __attribute__((ext_vector_type(8))) _Float16 f16x8;
typedef __attribute__((ext_vector_type(4))) float    f32x4;

typedef const __attribute__((address_space(1))) void* gas_t;
typedef __attribute__((address_space(3))) void*       las_t;

__device__ __forceinline__ void gl16(const f16* g, f16* l) {
    __builtin_amdgcn_global_load_lds((gas_t)g, (las_t)l, 16, 0, 0);
}

// ===========================================================================
// P: fp32 -> f16 (hi only), vectorized
// ===========================================================================
__global__ __launch_bounds__(256) void p_cvt(const float* __restrict__ in,
                                             f16* __restrict__ hi, int n4) {
    int i = blockIdx.x * 256 + threadIdx.x;
    if (i >= n4) return;
    float4 v = ((const float4*)in)[i];
    f16x4 hv; hv[0] = (f16)v.x; hv[1] = (f16)v.y; hv[2] = (f16)v.z; hv[3] = (f16)v.w;
    ((f16x4*)hi)[i] = hv;
}

// --- W fp32 -> hi/lo fp16 (small) -----------------------------------------
__global__ __launch_bounds__(256) void p_split(const float* __restrict__ in,
                                               f16* __restrict__ hi,
                                               f16* __restrict__ lo, int n4) {
    int i = blockIdx.x * 256 + threadIdx.x;
    if (i >= n4) return;
    float4 v = ((const float4*)in)[i];
    f16 h0 = (f16)v.x, h1 = (f16)v.y, h2 = (f16)v.z, h3 = (f16)v.w;
    f16x4 hv; hv[0] = h0; hv[1] = h1; hv[2] = h2; hv[3] = h3;
    f16x4 lv;
    lv[0] = (f16)(v.x - (float)h0); lv[1] = (f16)(v.y - (float)h1);
    lv[2] = (f16)(v.z - (float)h2); lv[3] = (f16)(v.w - (float)h3);
    ((f16x4*)hi)[i] = hv;
    ((f16x4*)lo)[i] = lv;
}

// ===========================================================================
// P: KV = concat(sp,ms) -> KVhi [b][2C][L] f16 + KVT [b][L][2C] f16.
// v3: 4 tiles per block, LDS double-buffer, lgkmcnt-only barrier so next
// tile's global loads stay in flight across it. Transposed b16 writes are
// XOR-swizzled (col = r ^ (q<<4)); b128 reads un-XOR with (g*8)^(l&48).
// Both LDS phases conflict-free.
// ===========================================================================
__global__ __launch_bounds__(256) void p_kv(const float* __restrict__ sp,
                                            const float* __restrict__ ms,
                                            f16* __restrict__ kvhi,
                                            f16* __restrict__ kvt) {
    __shared__ __align__(16) f16 tile[2][64][72];
    const int b = blockIdx.z, c0 = blockIdx.y * 64, lb = blockIdx.x * 256;
    const int t = threadIdx.x;
    const int r = t >> 2, q = t & 3;
    const float* src = (c0 + r < Cc)
        ? sp + ((size_t)b * Cc + c0 + r) * Ll
        : ms + ((size_t)b * Cc + (c0 + r - Cc)) * Ll;
    const int lr_ = t >> 3, g = t & 7;
    const int rw = r ^ (q << 4);            // swizzled write column

    float4 va[4], vb[4];
    #pragma unroll
    for (int i = 0; i < 4; ++i)
        va[i] = *(const float4*)(src + lb + q * 16 + i * 4);

    #pragma unroll
    for (int it = 0; it < 4; ++it) {
        const int l0 = lb + it * 64;
        const int p = it & 1;
        if (it < 3) {                        // prefetch next tile (stays in
            #pragma unroll                   // flight across the barrier)
            for (int i = 0; i < 4; ++i)
                vb[i] = *(const float4*)(src + l0 + 64 + q * 16 + i * 4);
        }
        f16 h[16];
        #pragma unroll
        for (int i = 0; i < 4; ++i) {
            float4 v = va[i];
            h[i * 4 + 0] = (f16)v.x; h[i * 4 + 1] = (f16)v.y;
            h[i * 4 + 2] = (f16)v.z; h[i * 4 + 3] = (f16)v.w;
        }
        f16* dst = &kvhi[((size_t)b * KV2 + c0 + r) * Ll + l0 + q * 16];
        *(f16x8*)dst       = *(const f16x8*)&h[0];
        *(f16x8*)(dst + 8) = *(const f16x8*)&h[8];
        #pragma unroll
        for (int e = 0; e < 16; ++e)
            tile[p][q * 16 + e][rw] = h[e];
        asm volatile("s_waitcnt lgkmcnt(0)" ::: "memory");   // NOT vmcnt
        __builtin_amdgcn_s_barrier();
        #pragma unroll
        for (int pp = 0; pp < 2; ++pp) {
            const int l = lr_ + 32 * pp;
            f16x8 o = *(const f16x8*)&tile[p][l][(g * 8) ^ (l & 48)];
            *(f16x8*)&kvt[((size_t)b * Ll + l0 + l) * KV2 + c0 + g * 8] = o;
        }
        if (it < 3) {
            #pragma unroll
            for (int i = 0; i < 4; ++i) va[i] = vb[i];
        }
    }
}

// ===========================================================================
// 256x256-tile NT MFMA GEMM, 8-phase schedule (T1+T2+T3+T4+T5):
//   - 512 threads = 8 waves (2M x 4N), per-wave C = 128x64, BK=64
//   - LDS: ring of 8 half-tile slots (128 rows x 64 f16 = 16KB) = 128KB
//   - counted vmcnt(6) only at tile boundary; 3-bit XOR LDS swizzle
// EPI 0: f16 out * (scale*L^-0.5)  (k1, split-K slice KSV)
// EPI 2: fp32 out + bias[m]        (k4)
// ===========================================================================
template<int KD, int NBN, int EPI, int KSV>
__global__ __launch_bounds__(512, 2) void gemm256(
    const f16* __restrict__ Ah, size_t sAb, int lda,
    const f16* __restrict__ Bh, size_t sBb, int ldb,
    const float* __restrict__ scale_ptr, const float* __restrict__ bias,
    float* __restrict__ Cf, f16* __restrict__ Chi,
    size_t sCb, size_t sliceC, int ldc)
{
    constexpr int NT = KD / 64;
    __shared__ __align__(16) f16 ring[8][128 * 64];

    // XCD-aware bijective swizzle (grid = 256 = 32/XCD)
    int wg = blockIdx.x;
    const int chunk = (int)gridDim.x >> 3;
    wg = (wg & 7) * chunk + (wg >> 3);
    const int m0 = (wg & 1) * 256; wg >>= 1;
    const int n0 = (wg % NBN) * 256; wg /= NBN;
    const int b = wg / KSV, s = wg % KSV;

    const int t = threadIdx.x;
    const int w = t >> 6, lane = t & 63;
    const int quad = lane >> 4, lr = lane & 15;
    const int wm = (w >> 2) * 128, wn = (w & 3) * 64;
    const int tA = 2 + (w >> 2);           // wave's A half-type
    const int tB = (w & 3) >> 1;           // wave's B half-type
    const int brow = (w & 1) * 64;         // B row base within half
    const int srow = lane >> 3, sslot = (lane & 7) ^ srow;
    const int x7 = lr & 7;

    const f16* gA = Ah + (size_t)b * sAb + (size_t)s * KD
                  + (size_t)(m0 + w * 8 + srow) * lda + sslot * 8;
    const f16* gB = Bh + (size_t)b * sBb + (size_t)s * KD
                  + (size_t)(n0 + w * 8 + srow) * ldb + sslot * 8;
    f16* const ld0 = &ring[0][0] + (w * 8) * 64;   // wave-uniform LDS base

    auto stA = [&](int tile, int half) {
        if (tile >= NT) return;
        f16* d = ld0 + ((tile * 4 + 2 + half) & 7) * (128 * 64);
        const f16* g = gA + (size_t)(half * 128) * lda + tile * 64;
        gl16(g, d);
        gl16(g + (size_t)64 * lda, d + 64 * 64);
    };
    auto stB = [&](int tile, int half) {
        if (tile >= NT) return;
        f16* d = ld0 + ((tile * 4 + half) & 7) * (128 * 64);
        const f16* g = gB + (size_t)(half * 128) * ldb + tile * 64;
        gl16(g, d);
        gl16(g + (size_t)64 * ldb, d + 64 * 64);
    };

    f32x4 acc[8][4];
    #pragma unroll
    for (int i = 0; i < 8; ++i)
        #pragma unroll
        for (int j = 0; j < 4; ++j) {
            acc[i][j][0] = 0.f; acc[i][j][1] = 0.f;
            acc[i][j][2] = 0.f; acc[i][j][3] = 0.f;
        }

    // ---- prologue: issue tile0 fully + B0,B1,A0 of tile1; confirm tile0
    stB(0, 0); stB(0, 1); stA(0, 0); stA(0, 1);
    stB(1, 0); stB(1, 1); stA(1, 0);
    asm volatile("s_waitcnt vmcnt(6)" ::: "memory");
    __builtin_amdgcn_s_barrier();

    f16x8 a[4][2], bf[4][2];

    #pragma unroll 2
    for (int T = 0; T < NT; ++T) {
        const f16* sAp = &ring[(T * 4 + tA) & 7][0];
        const f16* sBp = &ring[(T * 4 + tB) & 7][0];

        // ---------- phase 0: read A(i0-3) + all B frags; stage A1(T+1)
        #pragma unroll
        for (int ii = 0; ii < 4; ++ii)
            #pragma unroll
            for (int ks = 0; ks < 2; ++ks)
                a[ii][ks] = *(const f16x8*)&sAp[(ii * 16 + lr) * 64
                             + ((((ks << 2) | quad) ^ x7) << 3)];
        #pragma unroll
        for (int j = 0; j < 4; ++j)
            #pragma unroll
            for (int ks = 0; ks < 2; ++ks)
                bf[j][ks] = *(const f16x8*)&sBp[(brow + j * 16 + lr) * 64
                             + ((((ks << 2) | quad) ^ x7) << 3)];
        stA(T + 1, 1);
        asm volatile("s_waitcnt lgkmcnt(0)" ::: "memory");
        __builtin_amdgcn_s_barrier();
        __builtin_amdgcn_s_setprio(1);
        #pragma unroll
        for (int ii = 0; ii < 4; ++ii)
            #pragma unroll
            for (int j = 0; j < 2; ++j)
                #pragma unroll
                for (int ks = 0; ks < 2; ++ks)
                    acc[ii][j] = __builtin_amdgcn_mfma_f32_16x16x32_f16(
                                     a[ii][ks], bf[j][ks], acc[ii][j], 0, 0, 0);
        __builtin_amdgcn_s_setprio(0);
        __builtin_amdgcn_s_barrier();

        // ---------- phase 1: stage B0(T+2); MFMA q1 (i0-3 x j2-3)
        stB(T + 2, 0);
        __builtin_amdgcn_s_barrier();
        __builtin_amdgcn_s_setprio(1);
        #pragma unroll
        for (int ii = 0; ii < 4; ++ii)
            #pragma unroll
            for (int j = 0; j < 2; ++j)
                #pragma unroll
                for (int ks = 0; ks < 2; ++ks)
                    acc[ii][2 + j] = __builtin_amdgcn_mfma_f32_16x16x32_f16(
                                     a[ii][ks], bf[2 + j][ks], acc[ii][2 + j], 0, 0, 0);
        __builtin_amdgcn_s_setprio(0);
        __builtin_amdgcn_s_barrier();

        // ---------- phase 2: read A(i4-7); stage B1(T+2); MFMA q2
        #pragma unroll
        for (int ii = 0; ii < 4; ++ii)
            #pragma unroll
            for (int ks = 0; ks < 2; ++ks)
                a[ii][ks] = *(const f16x8*)&sAp[((ii + 4) * 16 + lr) * 64
                             + ((((ks << 2) | quad) ^ x7) << 3)];
        stB(T + 2, 1);
        asm volatile("s_waitcnt lgkmcnt(0)" ::: "memory");
        __builtin_amdgcn_s_barrier();
        __builtin_amdgcn_s_setprio(1);
        #pragma unroll
        for (int ii = 0; ii < 4; ++ii)
            #pragma unroll
            for (int j = 0; j < 2; ++j)
                #pragma unroll
                for (int ks = 0; ks < 2; ++ks)
                    acc[4 + ii][j] = __builtin_amdgcn_mfma_f32_16x16x32_f16(
                                     a[ii][ks], bf[j][ks], acc[4 + ii][j], 0, 0, 0);
        __builtin_amdgcn_s_setprio(0);
        __builtin_amdgcn_s_barrier();

        // ---------- phase 3: stage A0(T+2); boundary vmcnt; MFMA q3
        stA(T + 2, 0);
        if (T + 2 < NT) { asm volatile("s_waitcnt vmcnt(6)" ::: "memory"); }
        else            { asm volatile("s_waitcnt vmcnt(0)" ::: "memory"); }
        __builtin_amdgcn_s_barrier();
        __builtin_amdgcn_s_setprio(1);
        #pragma unroll
        for (int ii = 0; ii < 4; ++ii)
            #pragma unroll
            for (int j = 0; j < 2; ++j)
                #pragma unroll
                for (int ks = 0; ks < 2; ++ks)
                    acc[4 + ii][2 + j] = __builtin_amdgcn_mfma_f32_16x16x32_f16(
                                     a[ii][ks], bf[2 + j][ks], acc[4 + ii][2 + j], 0, 0, 0);
        __builtin_amdgcn_s_setprio(0);
        __builtin_amdgcn_s_barrier();
    }

    if constexpr (EPI == 0) {
        const float alpha = scale_ptr[0] * 0.015625f;
        f16* Cs = Chi + (size_t)s * sliceC + (size_t)b * sCb;
        #pragma unroll
        for (int i = 0; i < 8; ++i)
            #pragma unroll
            for (int j = 0; j < 4; ++j) {
                const int n = n0 + wn + j * 16 + lr;
                #pragma unroll
                for (int r = 0; r < 4; ++r) {
                    const int m = m0 + wm + i * 16 + quad * 4 + r;
                    Cs[(size_t)m * ldc + n] = (f16)(alpha * acc[i][j][r]);
                }
            }
    } else {
        float* Co = Cf + (size_t)b * sCb;
        #pragma unroll
        for (int i = 0; i < 8; ++i)
            #pragma unroll
            for (int j = 0; j < 4; ++j) {
                const int n = n0 + wn + j * 16 + lr;
                #pragma unroll
                for (int r = 0; r < 4; ++r) {
                    const int m = m0 + wm + i * 16 + quad * 4 + r;
                    Co[(size_t)m * ldc + n] = acc[i][j][r] + bias[m];
                }
            }
    }
}

// ===========================================================================
// 128x128-tile NT MFMA GEMM (round-1 structure) — kept for K3 (LO path).
// ===========================================================================
template<int KD, int NBN, int EPI, bool LO, int KSV>
__global__ __launch_bounds__(256, 3) void gemm_mfma(
    const f16* __restrict__ Ah, const f16* __restrict__ Al, size_t sAb, int lda,
    const f16* __restrict__ Bh, size_t sBb, int ldb,
    const float* __restrict__ scale_ptr, const float* __restrict__ bias,
    float* __restrict__ Cf, f16* __restrict__ Chi,
    size_t sCb, size_t sliceC, int ldc)
{
    __shared__ __align__(16) f16 sA[128 * 64];
    __shared__ __align__(16) f16 sB[128 * 64];
    __shared__ __align__(16) f16 sL[LO ? 128 * 64 : 8];

    int wg = blockIdx.x;
    const int chunk = (int)gridDim.x >> 3;
    wg = (wg & 7) * chunk + (wg >> 3);
    const int m0 = (wg & 3) * 128; wg >>= 2;
    const int n0 = (wg % NBN) * 128; wg /= NBN;
    const int b  = wg / KSV, s = wg % KSV;

    const int t = threadIdx.x;
    const int w = t >> 6, lane = t & 63;
    const int quad = lane >> 4, lr = lane & 15;
    const int wm = (w & 1) * 64, wn = (w >> 1) * 64;
    const int sr = lane >> 3, sc = lane & 7;
    const int swb = (sc ^ sr) << 3;
    const int x7 = lr & 7;

    const f16* gA = Ah + (size_t)b * sAb + (size_t)s * KD
                  + (size_t)(m0 + w * 8 + sr) * lda + swb;
    const f16* gB = Bh + (size_t)b * sBb + (size_t)s * KD
                  + (size_t)(n0 + w * 8 + sr) * ldb + swb;
    const f16* gL = LO ? (Al + (size_t)(m0 + w * 8 + sr) * lda + swb) : nullptr;

    f32x4 acc[4][4];
    #pragma unroll
    for (int i = 0; i < 4; ++i)
        #pragma unroll
        for (int j = 0; j < 4; ++j) {
            acc[i][j][0] = 0.f; acc[i][j][1] = 0.f;
            acc[i][j][2] = 0.f; acc[i][j][3] = 0.f;
        }

    for (int k0 = 0; k0 < KD; k0 += 64) {
        #pragma unroll
        for (int i = 0; i < 4; ++i) {
            gl16(gA + k0 + (size_t)(i * 32) * lda, &sA[(i * 32 + w * 8) * 64]);
            gl16(gB + k0 + (size_t)(i * 32) * ldb, &sB[(i * 32 + w * 8) * 64]);
            if constexpr (LO)
                gl16(gL + k0 + (size_t)(i * 32) * lda, &sL[(i * 32 + w * 8) * 64]);
        }
        asm volatile("s_waitcnt vmcnt(0)" ::: "memory");
        __syncthreads();
        #pragma unroll
        for (int ks = 0; ks < 2; ++ks) {
            f16x8 af[4], bfr[4];
            #pragma unroll
            for (int i = 0; i < 4; ++i)
                af[i] = *(const f16x8*)&sA[(wm + i * 16 + lr) * 64
                         + ((((ks << 2) | quad) ^ x7) << 3)];
            #pragma unroll
            for (int j = 0; j < 4; ++j)
                bfr[j] = *(const f16x8*)&sB[(wn + j * 16 + lr) * 64
                         + ((((ks << 2) | quad) ^ x7) << 3)];
            #pragma unroll
            for (int i = 0; i < 4; ++i)
                #pragma unroll
                for (int j = 0; j < 4; ++j)
                    acc[i][j] = __builtin_amdgcn_mfma_f32_16x16x32_f16(
                                    af[i], bfr[j], acc[i][j], 0, 0, 0);
            if constexpr (LO) {
                f16x8 lf[4];
                #pragma unroll
                for (int i = 0; i < 4; ++i)
                    lf[i] = *(const f16x8*)&sL[(wm + i * 16 + lr) * 64
                             + ((((ks << 2) | quad) ^ x7) << 3)];
                #pragma unroll
                for (int i = 0; i < 4; ++i)
                    #pragma unroll
                    for (int j = 0; j < 4; ++j)
                        acc[i][j] = __builtin_amdgcn_mfma_f32_16x16x32_f16(
                                        lf[i], bfr[j], acc[i][j], 0, 0, 0);
            }
        }
        __syncthreads();
    }

    if constexpr (EPI == 0) {
        const float alpha = scale_ptr[0] * 0.015625f;
        f16* Cs = Chi + (size_t)s * sliceC + (size_t)b * sCb;
        #pragma unroll
        for (int i = 0; i < 4; ++i)
            #pragma unroll
            for (int j = 0; j < 4; ++j) {
                const int n = n0 + wn + j * 16 + lr;
                #pragma unroll
                for (int r = 0; r < 4; ++r) {
                    const int m = m0 + wm + i * 16 + quad * 4 + r;
                    Cs[(size_t)m * ldc + n] = (f16)(alpha * acc[i][j][r]);
                }
            }
    } else if constexpr (EPI == 1) {
        f16* Cs = Chi + (size_t)b * sCb;
        #pragma unroll
        for (int i = 0; i < 4; ++i)
            #pragma unroll
            for (int j = 0; j < 4; ++j) {
                const int n = n0 + wn + j * 16 + lr;
                #pragma unroll
                for (int r = 0; r < 4; ++r) {
                    const int m = m0 + wm + i * 16 + quad * 4 + r;
                    Cs[(size_t)m * ldc + n] = (f16)acc[i][j][r];
                }
            }
    } else {
        float* Co = Cf + (size_t)b * sCb;
        #pragma unroll
        for (int i = 0; i < 4; ++i)
            #pragma unroll
            for (int j = 0; j < 4; ++j) {
                const int n = n0 + wn + j * 16 + lr;
                #pragma unroll
                for (int r = 0; r < 4; ++r) {
                    const int m = m0 + wm + i * 16 + quad * 4 + r;
                    Co[(size_t)m * ldc + n] = acc[i][j][r] + bias[m];
                }
            }
    }
}

// ===========================================================================
// K2 v2: single-pass softmax+transpose. Pass 1: sum KS slices in registers,
// max/sum reduce, write exp*inv (f32) to swizzled LDS row buffer. One
// barrier. Pass 2: conflict-free b32 column gather + coalesced f16 store.
// ===========================================================================
__global__ __launch_bounds__(256) void k2_softmax_t(const f16* __restrict__ attnP,
                                                    f16* __restrict__ attnT) {
    __shared__ __align__(16) float rowe[16][1024];   // 64 KB
    const int b = blockIdx.y, c0 = blockIdx.x * 16;
    const int t = threadIdx.x, w = t >> 6, lane = t & 63;
    const size_t sS = (size_t)Bq * Cc * KV2;

    #pragma unroll
    for (int rr = 0; rr < 4; ++rr) {
        const int r = w * 4 + rr;
        const f16* base = attnP + ((size_t)b * Cc + c0 + r) * KV2;
        float v[16];
        #pragma unroll
        for (int i = 0; i < 2; ++i) {
            f16x8 u = *(const f16x8*)(base + (lane + 64 * i) * 8);
            #pragma unroll
            for (int j = 0; j < 8; ++j) v[i * 8 + j] = (float)u[j];
        }
        #pragma unroll
        for (int s = 1; s < KS; ++s) {
            const f16* bs = base + (size_t)s * sS;
            #pragma unroll
            for (int i = 0; i < 2; ++i) {
                f16x8 u = *(const f16x8*)(bs + (lane + 64 * i) * 8);
                #pragma unroll
                for (int j = 0; j < 8; ++j) v[i * 8 + j] += (float)u[j];
            }
        }
        float m = -3.4e38f;
        #pragma unroll
        for (int i = 0; i < 16; ++i) m = fmaxf(m, v[i]);
        #pragma unroll
        for (int off = 32; off; off >>= 1) m = fmaxf(m, __shfl_xor(m, off));
        float s = 0.f;
        float e[16];
        #pragma unroll
        for (int i = 0; i < 16; ++i) { e[i] = __expf(v[i] - m); s += e[i]; }
        #pragma unroll
        for (int off = 32; off; off >>= 1) s += __shfl_xor(s, off);
        const float iv = 1.0f / s;
        // write exp*inv to LDS, 16B-group XOR swizzle (8 lanes/bank-group)
        #pragma unroll
        for (int i = 0; i < 2; ++i)
            #pragma unroll
            for (int j4 = 0; j4 < 2; ++j4) {
                const int g = (lane + 64 * i) * 2 + j4;
                const int gs = g ^ ((g >> 3) & 7);
                float4 o;
                o.x = e[i * 8 + j4 * 4 + 0] * iv; o.y = e[i * 8 + j4 * 4 + 1] * iv;
                o.z = e[i * 8 + j4 * 4 + 2] * iv; o.w = e[i * 8 + j4 * 4 + 3] * iv;
                *(float4*)&rowe[r][gs * 4] = o;
            }
    }
    __syncthreads();

    // transpose out: thread pair covers one n (16 c = 32B); 8 iters over n
    const int half = t & 1;
    #pragma unroll
    for (int nt = 0; nt < 8; ++nt) {
        const int n = nt * 128 + (t >> 1);
        const int g = n >> 2, gs = g ^ ((g >> 3) & 7);
        const int sc = gs * 4 + (n & 3);
        f16x8 hv;
        #pragma unroll
        for (int cc = 0; cc < 8; ++cc)
            hv[cc] = (f16)rowe[half * 8 + cc][sc];
        *(f16x8*)&attnT[((size_t)b * KV2 + n) * Cc + c0 + half * 8] = hv;
    }
}

// ===========================================================================
// FALLBACK PATH (fp32, needs only 33.6 MB)
// ===========================================================================
#define BM 64
#define BN 64
#define BK 32
#define PAD 4

__device__ __forceinline__ const float* kv_row(const float* __restrict__ sp,
                                               const float* __restrict__ ms,
                                               int b, int k) {
    return (k < Cc) ? (sp + ((size_t)b * Cc + k) * Ll)
                    : (ms + ((size_t)b * Cc + (k - Cc)) * Ll);
}

__global__ __launch_bounds__(256) void k1_logits(const float* __restrict__ x,
                                                 const float* __restrict__ sp,
                                                 const float* __restrict__ ms,
                                                 const float* __restrict__ scale,
                                                 float* __restrict__ attn) {
    __shared__ __align__(16) float As[BK][BM + PAD];
    __shared__ __align__(16) float Bs[BK][BN + PAD];
    const int b = blockIdx.z, m0 = blockIdx.y * BM, n0 = blockIdx.x * BN;
    const int t = threadIdx.x, tx = t & 15, ty = t >> 4, q = t & 7, r = t >> 3;
    const float alpha = scale[0] * (1.0f / 64.0f);
    const float* Abase = x + (size_t)b * Cc * Ll;
    float acc[4][4] = {};
    for (int k0 = 0; k0 < Ll; k0 += BK) {
        #pragma unroll
        for (int hh = 0; hh < 2; ++hh) {
            const int rw = r + 32 * hh;
            float4 v = *(const float4*)(Abase + (size_t)(m0 + rw) * Ll + k0 + 4 * q);
            As[4*q+0][rw] = v.x; As[4*q+1][rw] = v.y; As[4*q+2][rw] = v.z; As[4*q+3][rw] = v.w;
        }
        #pragma unroll
        for (int hh = 0; hh < 2; ++hh) {
            const int rw = r + 32 * hh;
            const float* Brow = kv_row(sp, ms, b, n0 + rw);
            float4 v = *(const float4*)(Brow + k0 + 4 * q);
            Bs[4*q+0][rw] = v.x; Bs[4*q+1][rw] = v.y; Bs[4*q+2][rw] = v.z; Bs[4*q+3][rw] = v.w;
        }
        __syncthreads();
        #pragma unroll
        for (int k = 0; k < BK; ++k) {
            float a[4], bb[4];
            *(float4*)a  = *(const float4*)&As[k][4 * ty];
            *(float4*)bb = *(const float4*)&Bs[k][4 * tx];
            #pragma unroll
            for (int i = 0; i < 4; ++i)
                #pragma unroll
                for (int j = 0; j < 4; ++j) acc[i][j] += a[i] * bb[j];
        }
        __syncthreads();
    }
    #pragma unroll
    for (int i = 0; i < 4; ++i) {
        const int m = m0 + 4 * ty + i;
        float4 o;
        o.x = alpha * acc[i][0]; o.y = alpha * acc[i][1];
        o.z = alpha * acc[i][2]; o.w = alpha * acc[i][3];
        *(float4*)(attn + ((size_t)b * Cc + m) * KV2 + n0 + 4 * tx) = o;
    }
}

__global__ __launch_bounds__(256) void k2_softmax(float* __restrict__ attn) {
    float* p = attn + (size_t)blockIdx.x * KV2;
    const int t = threadIdx.x, lane = t & 63, wv = t >> 6;
    float4 v = ((const float4*)p)[t];
    float m = fmaxf(fmaxf(v.x, v.y), fmaxf(v.z, v.w));
    #pragma unroll
    for (int off = 32; off; off >>= 1) m = fmaxf(m, __shfl_down(m, off));
    __shared__ float redm[4];
    if (lane == 0) redm[wv] = m;
    __syncthreads();
    m = fmaxf(fmaxf(redm[0], redm[1]), fmaxf(redm[2], redm[3]));
    v.x = __expf(v.x - m); v.y = __expf(v.y - m);
    v.z = __expf(v.z - m); v.w = __expf(v.w - m);
    float s = v.x + v.y + v.z + v.w;
    #pragma unroll
    for (int off = 32; off; off >>= 1) s += __shfl_down(s, off);
    __shared__ float reds[4];
    if (lane == 0) reds[wv] = s;
    __syncthreads();
    s = reds[0] + reds[1] + reds[2] + reds[3];
    const float inv = 1.0f / s;
    v.x *= inv; v.y *= inv; v.z *= inv; v.w *= inv;
    ((float4*)p)[t] = v;
}

__global__ __launch_bounds__(256) void k3_wattn(const float* __restrict__ W,
                                                const float* __restrict__ attn,
                                                float* __restrict__ attn2) {
    __shared__ __align__(16) float As[BK][BM + PAD];
    __shared__ __align__(16) float Bs[BK][BN];
    const int b = blockIdx.z, m0 = blockIdx.y * BM, n0 = blockIdx.x * BN;
    const int t = threadIdx.x, tx = t & 15, ty = t >> 4;
    const int q = t & 7, r = t >> 3, c4 = t & 15, kr = t >> 4;
    const float* Bbase = attn + (size_t)b * Cc * KV2;
    float acc[4][4] = {};
    for (int k0 = 0; k0 < Cc; k0 += BK) {
        #pragma unroll
        for (int hh = 0; hh < 2; ++hh) {
            const int rw = r + 32 * hh;
            float4 v = *(const float4*)(W + (size_t)(m0 + rw) * Cc + k0 + 4 * q);
            As[4*q+0][rw] = v.x; As[4*q+1][rw] = v.y; As[4*q+2][rw] = v.z; As[4*q+3][rw] = v.w;
        }
        #pragma unroll
        for (int hh = 0; hh < 2; ++hh) {
            const int k = kr + 16 * hh;
            float4 v = *(const float4*)(Bbase + (size_t)(k0 + k) * KV2 + n0 + 4 * c4);
            *(float4*)&Bs[k][4 * c4] = v;
        }
        __syncthreads();
        #pragma unroll
        for (int k = 0; k < BK; ++k) {
            float a[4], bb[4];
            *(float4*)a  = *(const float4*)&As[k][4 * ty];
            *(float4*)bb = *(const float4*)&Bs[k][4 * tx];
            #pragma unroll
            for (int i = 0; i < 4; ++i)
                #pragma unroll
                for (int j = 0; j < 4; ++j) acc[i][j] += a[i] * bb[j];
        }
        __syncthreads();
    }
    #pragma unroll
    for (int i = 0; i < 4; ++i) {
        const int m = m0 + 4 * ty + i;
        float4 o;
        o.x = acc[i][0]; o.y = acc[i][1]; o.z = acc[i][2]; o.w = acc[i][3];
        *(float4*)(attn2 + ((size_t)b * Cc + m) * KV2 + n0 + 4 * tx) = o;
    }
}

__global__ __launch_bounds__(256) void k4_out(const float* __restrict__ attn2,
                                              const float* __restrict__ sp,
                                              const float* __restrict__ ms,
                                              const float* __restrict__ bias,
                                              float* __restrict__ out) {
    __shared__ __align__(16) float As[BK][BM + PAD];
    __shared__ __align__(16) float Bs[BK][BN];
    const int b = blockIdx.z, m0 = blockIdx.y * BM, n0 = blockIdx.x * BN;
    const int t = threadIdx.x, tx = t & 15, ty = t >> 4;
    const int q = t & 7, r = t >> 3, c4 = t & 15, kr = t >> 4;
    const float* Abase = attn2 + (size_t)b * Cc * KV2;
    float acc[4][4] = {};
    for (int k0 = 0; k0 < KV2; k0 += BK) {
        #pragma unroll
        for (int hh = 0; hh < 2; ++hh) {
            const int rw = r + 32 * hh;
            float4 v = *(const float4*)(Abase + (size_t)(m0 + rw) * KV2 + k0 + 4 * q);
            As[4*q+0][rw] = v.x; As[4*q+1][rw] = v.y; As[4*q+2][rw] = v.z; As[4*q+3][rw] = v.w;
        }
        #pragma unroll
        for (int hh = 0; hh < 2; ++hh) {
            const int k = kr + 16 * hh;
            const float* Brow = kv_row(sp, ms, b, k0 + k);
            float4 v = *(const float4*)(Brow + n0 + 4 * c4);
            *(float4*)&Bs[k][4 * c4] = v;
        }
        __syncthreads();
        #pragma unroll
        for (int k = 0; k < BK; ++k) {
            float a[4], bb[4];
            *(float4*)a  = *(const float4*)&As[k][4 * ty];
            *(float4*)bb = *(const float4*)&Bs[k][4 * tx];
            #pragma unroll
            for (int i = 0; i < 4; ++i)
                #pragma unroll
                for (int j = 0; j < 4; ++j) acc[i][j] += a[i] * bb[j];
        }
        __syncthreads();
    }
    #pragma unroll
    for (int i = 0; i < 4; ++i) {
        const int m = m0 + 4 * ty + i;
        const float bm = bias[m];
        float4 o;
        o.x = acc[i][0] + bm; o.y = acc[i][1] + bm;
        o.z = acc[i][2] + bm; o.w = acc[i][3] + bm;
        *(float4*)(out + ((size_t)b * Cc + m) * Ll + n0 + 4 * tx) = o;
    }
}

// ===========================================================================
extern "C" void kernel_launch(void* const* d_in, const int* in_sizes, int n_in,
                              void* d_out, int out_size, void* d_ws, size_t ws_size,
                              hipStream_t stream) {
    const float* x     = (const float*)d_in[0];
    const float* sp    = (const float*)d_in[1];
    const float* ms    = (const float*)d_in[2];
    const float* scale = (const float*)d_in[3];
    const float* W     = (const float*)d_in[4];
    const float* bias  = (const float*)d_in[5];
    float* out = (float*)d_out;

    const size_t NEED = 219152384;
    if (ws_size >= NEED) {
        char* ws = (char*)d_ws;
        f16* attnP = (f16*)ws;                      // KS*B*C*2C f16 = 33,554,432
        f16* Xhi   = (f16*)(ws + 33554432);         // 33,554,432
        f16* KVhi  = (f16*)(ws + 67108864);         // 67,108,864
        f16* KVT   = (f16*)(ws + 134217728);        // 67,108,864
        f16* Whi   = (f16*)(ws + 201326592);        //    524,288
        f16* Wlo   = (f16*)(ws + 201850880);        //    524,288
        f16* attnT = (f16*)(ws + 202375168);        //  8,388,608
        f16* A2hi  = (f16*)(ws + 210763776);        //  8,388,608

        dim3 blk(256);
        p_cvt  <<<dim3(16384),                  blk, 0, stream>>>(x, Xhi, Bq * Cc * Ll / 4);
        p_kv   <<<dim3(Ll / 256, KV2 / 64, Bq), blk, 0, stream>>>(sp, ms, KVhi, KVT);
        p_split<<<dim3(256),                    blk, 0, stream>>>(W, Whi, Wlo, Cc * Cc / 4);

        // K1: attnP[s][b][m][n] = alpha * X[b,m,:] . KV[b,n,:]  (split-K=4)
        gemm256<KSL, KV2 / 256, 0, KS>
            <<<dim3(2 * (KV2 / 256) * Bq * KS), dim3(512), 0, stream>>>(
            Xhi, (size_t)Cc * Ll, Ll,
            KVhi, (size_t)KV2 * Ll, Ll,
            scale, nullptr, nullptr, attnP,
            (size_t)Cc * KV2, (size_t)Bq * Cc * KV2, KV2);

        k2_softmax_t<<<dim3(Cc / 16, Bq), blk, 0, stream>>>(attnP, attnT);

        // K3: A2[b][m][k] = (Whi+Wlo)[m,:] . attnT[b,k,:]
        gemm_mfma<Cc, KV2 / 128, 1, true, 1>
            <<<dim3(4 * (KV2 / 128) * Bq), blk, 0, stream>>>(
            Whi, Wlo, (size_t)0, Cc,
            attnT, (size_t)KV2 * Cc, Cc,
            nullptr, nullptr, nullptr, A2hi,
            (size_t)Cc * KV2, (size_t)0, KV2);

        // K4: out[b][m][l] = A2[b,m,:] . KVT[b,l,:] + bias[m]
        gemm256<KV2, Ll / 256, 2, 1>
            <<<dim3(2 * (Ll / 256) * Bq), dim3(512), 0, stream>>>(
            A2hi, (size_t)Cc * KV2, KV2,
            KVT, (size_t)Ll * KV2, KV2,
            nullptr, bias, out, nullptr,
            (size_t)Cc * Ll, (size_t)0, Ll);
    } else {
        float* attn  = (float*)d_ws;
        float* attn2 = attn + (size_t)Bq * Cc * KV2;
        dim3 blk(256);
        k1_logits <<<dim3(KV2 / BN, Cc / BM, Bq), blk, 0, stream>>>(x, sp, ms, scale, attn);
        k2_softmax<<<dim3(Bq * Cc),               blk, 0, stream>>>(attn);
        k3_wattn  <<<dim3(KV2 / BN, Cc / BM, Bq), blk, 0, stream>>>(W, attn, attn2);
        k4_out    <<<dim3(Ll / BN, Cc / BM, Bq), blk, 0, stream>>>(attn2, sp, ms, bias, out);
    }
}